// Round 1
// baseline (387.862 us; speedup 1.0000x reference)
//
#include <hip/hip_runtime.h>
#include <math.h>

#define DMODEL 4096
#define THREED 12288
#define NHEAD 32
#define HDIM 128
#define NB 8
#define NPAGES 32
#define PAGEK 128

// ---------------------------------------------------------------------------
// Skinny GEMM partial: out_part[ks][b][col] = sum_{k in chunk} X[b][k]*W[k][col]
// X: [8][K], W: [K][N] row-major. One thread per column, k-split over blockIdx.y.
// ---------------------------------------------------------------------------
__global__ __launch_bounds__(256) void gemm_skinny_partial(
    const float* __restrict__ X, const float* __restrict__ W,
    float* __restrict__ part, int K, int N, int kchunk) {
  __shared__ float xs[8 * 256];
  const int col = blockIdx.x * 256 + threadIdx.x;
  const int k0 = blockIdx.y * kchunk;

  // stage x chunk in LDS
  #pragma unroll
  for (int b = 0; b < 8; ++b) {
    if (threadIdx.x < kchunk)
      xs[b * 256 + threadIdx.x] = X[b * K + k0 + threadIdx.x];
  }
  __syncthreads();

  float acc[8] = {0.f, 0.f, 0.f, 0.f, 0.f, 0.f, 0.f, 0.f};
  const float* wp = W + (size_t)k0 * N + col;
  #pragma unroll 4
  for (int k = 0; k < kchunk; ++k) {
    float w = wp[(size_t)k * N];
    #pragma unroll
    for (int b = 0; b < 8; ++b) acc[b] += xs[b * 256 + k] * w;
  }
  #pragma unroll
  for (int b = 0; b < 8; ++b)
    part[((size_t)blockIdx.y * 8 + b) * N + col] = acc[b];
}

// out[b][col] = bias[col] + sum_s part[s][b][col]
__global__ __launch_bounds__(256) void gemm_skinny_reduce(
    const float* __restrict__ part, const float* __restrict__ bias,
    float* __restrict__ out, int N, int ksplit) {
  int idx = blockIdx.x * 256 + threadIdx.x;  // over 8*N
  int b = idx / N, col = idx - b * N;
  float acc = bias[col];
  for (int s = 0; s < ksplit; ++s)
    acc += part[((size_t)s * 8 + b) * N + col];
  out[(size_t)b * N + col] = acc;
}

// ---------------------------------------------------------------------------
// Attention partial: one block per (page, head, batch). 256 threads = 4 waves.
// Each wave handles 32 keys of the 128-key page, 2 keys per iteration
// (lanes 0-31 -> even key, lanes 32-63 -> odd key; float4 per lane).
// Writes partial numerator y[128] and denom for this page.
// ---------------------------------------------------------------------------
__global__ __launch_bounds__(256) void attn_partial(
    const float* __restrict__ qkv,      // [8][12288]
    const float* __restrict__ k_cache,  // [32][8][32][128][128]
    const float* __restrict__ v_cache,
    float* __restrict__ part_y,         // [8*32*32][128]
    float* __restrict__ part_den) {     // [8*32*32]
  const int page = blockIdx.x;
  const int h = blockIdx.y;
  const int b = blockIdx.z;
  const int tid = threadIdx.x;
  const int wave = tid >> 6;
  const int lane = tid & 63;
  const int half = lane >> 5;  // 0: even key of pair, 1: odd
  const int l31 = lane & 31;

  const float scale = 0.08838834764831845f;  // 1/sqrt(128)

  const float4 qf =
      *(const float4*)(qkv + (size_t)b * THREED + h * HDIM + 4 * l31);

  const size_t base =
      ((((size_t)page * NB + b) * NHEAD + h) * PAGEK) * HDIM;
  const float* kp = k_cache + base;
  const float* vp = v_cache + base;

  float4 yacc = {0.f, 0.f, 0.f, 0.f};
  float den = 0.f;

  #pragma unroll 4
  for (int i = 0; i < 16; ++i) {
    const int key = wave * 32 + i * 2 + half;
    const float4 kf = *(const float4*)(kp + key * HDIM + 4 * l31);
    float s = qf.x * kf.x + qf.y * kf.y + qf.z * kf.z + qf.w * kf.w;
    // reduce across the 32 lanes of this half
    s += __shfl_xor(s, 1, 64);
    s += __shfl_xor(s, 2, 64);
    s += __shfl_xor(s, 4, 64);
    s += __shfl_xor(s, 8, 64);
    s += __shfl_xor(s, 16, 64);
    const float w = expf(s * scale);
    den += w;
    const float4 vf = *(const float4*)(vp + key * HDIM + 4 * l31);
    yacc.x += w * vf.x;
    yacc.y += w * vf.y;
    yacc.z += w * vf.z;
    yacc.w += w * vf.w;
  }

  // Per (wave,half) stream: lanes within a half all hold identical den.
  // Each lane owns dims [4*l31, 4*l31+4). Combine 8 streams via LDS.
  __shared__ float y_lds[8][HDIM];
  __shared__ float d_lds[8];
  const int row = wave * 2 + half;
  *(float4*)&y_lds[row][4 * l31] = yacc;
  if (l31 == 0) d_lds[row] = den;
  __syncthreads();

  if (tid < HDIM) {
    float y = 0.f;
    #pragma unroll
    for (int r = 0; r < 8; ++r) y += y_lds[r][tid];
    const int bhp = (b * NHEAD + h) * NPAGES + page;
    part_y[(size_t)bhp * HDIM + tid] = y;
    if (tid == 0) {
      float dd = 0.f;
      #pragma unroll
      for (int r = 0; r < 8; ++r) dd += d_lds[r];
      part_den[bhp] = dd;
    }
  }
}

// ---------------------------------------------------------------------------
// Attention reduce: per (b,h) combine 32 page partials + current-token k/v.
// 128 threads (one per dim).
// ---------------------------------------------------------------------------
__global__ __launch_bounds__(128) void attn_reduce(
    const float* __restrict__ qkv,
    const float* __restrict__ part_y, const float* __restrict__ part_den,
    float* __restrict__ yattn) {  // [8][4096]
  const int h = blockIdx.x;
  const int b = blockIdx.y;
  const int d = threadIdx.x;
  const int bh = b * NHEAD + h;
  const float scale = 0.08838834764831845f;

  float y = 0.f;
  #pragma unroll 4
  for (int p = 0; p < NPAGES; ++p)
    y += part_y[((size_t)bh * NPAGES + p) * HDIM + d];
  float den = 0.f;
  #pragma unroll 4
  for (int p = 0; p < NPAGES; ++p) den += part_den[bh * NPAGES + p];

  const float q = qkv[(size_t)b * THREED + h * HDIM + d];
  const float kc = qkv[(size_t)b * THREED + DMODEL + h * HDIM + d];
  const float vc = qkv[(size_t)b * THREED + 2 * DMODEL + h * HDIM + d];

  __shared__ float red[HDIM];
  red[d] = q * kc;
  __syncthreads();
  for (int s = 64; s > 0; s >>= 1) {
    if (d < s) red[d] += red[d + s];
    __syncthreads();
  }
  const float wn = expf(red[0] * scale);
  y = (y + wn * vc) / (den + wn);
  yattn[(size_t)b * DMODEL + h * HDIM + d] = y;
}

extern "C" void kernel_launch(void* const* d_in, const int* in_sizes, int n_in,
                              void* d_out, int out_size, void* d_ws,
                              size_t ws_size, hipStream_t stream) {
  const float* x = (const float*)d_in[0];
  const float* k_cache = (const float*)d_in[1];
  const float* v_cache = (const float*)d_in[2];
  const float* w_attn = (const float*)d_in[3];
  const float* b_attn = (const float*)d_in[4];
  const float* w_proj = (const float*)d_in[5];
  const float* b_proj = (const float*)d_in[6];
  float* out = (float*)d_out;
  float* ws = (float*)d_ws;

  // workspace layout (floats)
  float* qkv = ws;                        // 8*12288            = 98304
  float* g1p = qkv + 98304;               // 16*8*12288         = 1572864
  float* apy = g1p + 16 * 8 * THREED;     // 8192*128           = 1048576
  float* apd = apy + 8192 * HDIM;         // 8192
  float* yat = apd + 8192;                // 8*4096             = 32768
  float* g2p = yat + NB * DMODEL;         // 32*8*4096          = 1048576

  // 1) qkv = x @ w_attn + b_attn  (K=4096 split 16x256)
  gemm_skinny_partial<<<dim3(THREED / 256, 16), 256, 0, stream>>>(
      x, w_attn, g1p, DMODEL, THREED, 256);
  gemm_skinny_reduce<<<dim3(NB * THREED / 256), 256, 0, stream>>>(
      g1p, b_attn, qkv, THREED, 16);

  // 2) paged attention partials + reduce
  attn_partial<<<dim3(NPAGES, NHEAD, NB), 256, 0, stream>>>(
      qkv, k_cache, v_cache, apy, apd);
  attn_reduce<<<dim3(NHEAD, NB), 128, 0, stream>>>(qkv, apy, apd, yat);

  // 3) out = yattn @ w_proj + b_proj  (K=4096 split 32x128)
  gemm_skinny_partial<<<dim3(DMODEL / 256, 32), 256, 0, stream>>>(
      yat, w_proj, g2p, DMODEL, DMODEL, 128);
  gemm_skinny_reduce<<<dim3(NB * DMODEL / 256), 256, 0, stream>>>(
      g2p, b_proj, out, DMODEL, 32);
}

// Round 2
// 272.072 us; speedup vs baseline: 1.4256x; 1.4256x over previous
//
#include <hip/hip_runtime.h>
#include <math.h>

#define DMODEL 4096
#define THREED 12288
#define NHEAD 32
#define HDIM 128
#define NB 8
#define NPAGES 32
#define PAGEK 128

#if __has_builtin(__builtin_amdgcn_exp2f)
#define FAST_EXP2(x) __builtin_amdgcn_exp2f(x)
#else
#define FAST_EXP2(x) exp2f(x)
#endif

// log2(e) / sqrt(128)
#define SCALE_LOG2E (0.08838834764831845f * 1.44269504088896340736f)

// ---------------------------------------------------------------------------
// Skinny GEMM partial: part[s][b][col] = sum_{k in chunk s} X[b][k]*W[k][col]
// X: [8][K] (read via wave-uniform scalar loads), W: [K][N] row-major.
// Each thread owns 2 columns (float2 loads of W). k-split over blockIdx.y.
// ---------------------------------------------------------------------------
__global__ __launch_bounds__(256) void gemm_skinny_partial(
    const float* __restrict__ X, const float* __restrict__ W,
    float* __restrict__ part, int K, int N, int kchunk) {
  const int col = (blockIdx.x * 256 + threadIdx.x) * 2;
  const int k0 = blockIdx.y * kchunk;

  float2 acc[8];
  #pragma unroll
  for (int b = 0; b < 8; ++b) acc[b] = make_float2(0.f, 0.f);

  const float* wp = W + (size_t)k0 * N + col;
  const float* xp = X + k0;

  #pragma unroll 4
  for (int k = 0; k < kchunk; ++k) {
    const float2 w = *(const float2*)(wp + (size_t)k * N);
    #pragma unroll
    for (int b = 0; b < 8; ++b) {
      const float xv = xp[b * K + k];  // wave-uniform -> s_load, SGPR operand
      acc[b].x += xv * w.x;
      acc[b].y += xv * w.y;
    }
  }
  #pragma unroll
  for (int b = 0; b < 8; ++b)
    *(float2*)(part + ((size_t)blockIdx.y * 8 + b) * N + col) = acc[b];
}

// out[b][col] = bias[col] + sum_s part[s][b][col]
__global__ __launch_bounds__(256) void gemm_skinny_reduce(
    const float* __restrict__ part, const float* __restrict__ bias,
    float* __restrict__ out, int N, int ksplit) {
  int idx = blockIdx.x * 256 + threadIdx.x;  // over 8*N
  int b = idx / N, col = idx - b * N;
  float acc = bias[col];
  for (int s = 0; s < ksplit; ++s)
    acc += part[((size_t)s * 8 + b) * N + col];
  out[(size_t)b * N + col] = acc;
}

// ---------------------------------------------------------------------------
// Attention partial: one block per (page, head, batch). 256 threads = 4 waves.
// Each wave handles 32 keys, 2 per iteration (lane halves), float4 per lane.
// ---------------------------------------------------------------------------
__global__ __launch_bounds__(256) void attn_partial(
    const float* __restrict__ qkv,      // [8][12288]
    const float* __restrict__ k_cache,  // [32][8][32][128][128]
    const float* __restrict__ v_cache,
    float* __restrict__ part_y,         // [8*32*32][128]
    float* __restrict__ part_den) {     // [8*32*32]
  const int page = blockIdx.x;
  const int h = blockIdx.y;
  const int b = blockIdx.z;
  const int tid = threadIdx.x;
  const int wave = tid >> 6;
  const int lane = tid & 63;
  const int half = lane >> 5;
  const int l31 = lane & 31;

  const float4 qf =
      *(const float4*)(qkv + (size_t)b * THREED + h * HDIM + 4 * l31);

  const size_t base = ((((size_t)page * NB + b) * NHEAD + h) * PAGEK) * HDIM;
  const float* kp = k_cache + base;
  const float* vp = v_cache + base;

  float4 yacc = {0.f, 0.f, 0.f, 0.f};
  float den = 0.f;

  #pragma unroll 4
  for (int i = 0; i < 16; ++i) {
    const int key = wave * 32 + i * 2 + half;
    const float4 kf = *(const float4*)(kp + key * HDIM + 4 * l31);
    const float4 vf = *(const float4*)(vp + key * HDIM + 4 * l31);
    float s = qf.x * kf.x + qf.y * kf.y + qf.z * kf.z + qf.w * kf.w;
    s += __shfl_xor(s, 1, 64);
    s += __shfl_xor(s, 2, 64);
    s += __shfl_xor(s, 4, 64);
    s += __shfl_xor(s, 8, 64);
    s += __shfl_xor(s, 16, 64);
    const float w = FAST_EXP2(s * SCALE_LOG2E);
    den += w;
    yacc.x += w * vf.x;
    yacc.y += w * vf.y;
    yacc.z += w * vf.z;
    yacc.w += w * vf.w;
  }

  __shared__ float y_lds[8][HDIM];
  __shared__ float d_lds[8];
  const int row = wave * 2 + half;
  *(float4*)&y_lds[row][4 * l31] = yacc;
  if (l31 == 0) d_lds[row] = den;
  __syncthreads();

  if (tid < HDIM) {
    float y = 0.f;
    #pragma unroll
    for (int r = 0; r < 8; ++r) y += y_lds[r][tid];
    const int bhp = (b * NHEAD + h) * NPAGES + page;
    part_y[(size_t)bhp * HDIM + tid] = y;
    if (tid == 0) {
      float dd = 0.f;
      #pragma unroll
      for (int r = 0; r < 8; ++r) dd += d_lds[r];
      part_den[bhp] = dd;
    }
  }
}

// ---------------------------------------------------------------------------
// Attention reduce: per (b,h) combine 32 page partials + current-token k/v.
// ---------------------------------------------------------------------------
__global__ __launch_bounds__(128) void attn_reduce(
    const float* __restrict__ qkv,
    const float* __restrict__ part_y, const float* __restrict__ part_den,
    float* __restrict__ yattn) {  // [8][4096]
  const int h = blockIdx.x;
  const int b = blockIdx.y;
  const int d = threadIdx.x;
  const int bh = b * NHEAD + h;

  float y = 0.f;
  #pragma unroll 4
  for (int p = 0; p < NPAGES; ++p)
    y += part_y[((size_t)bh * NPAGES + p) * HDIM + d];
  float den = 0.f;
  #pragma unroll 4
  for (int p = 0; p < NPAGES; ++p) den += part_den[bh * NPAGES + p];

  const float q = qkv[(size_t)b * THREED + h * HDIM + d];
  const float kc = qkv[(size_t)b * THREED + DMODEL + h * HDIM + d];
  const float vc = qkv[(size_t)b * THREED + 2 * DMODEL + h * HDIM + d];

  __shared__ float red[HDIM];
  red[d] = q * kc;
  __syncthreads();
  for (int s = 64; s > 0; s >>= 1) {
    if (d < s) red[d] += red[d + s];
    __syncthreads();
  }
  const float wn = FAST_EXP2(red[0] * SCALE_LOG2E);
  y = (y + wn * vc) / (den + wn);
  yattn[(size_t)b * DMODEL + h * HDIM + d] = y;
}

extern "C" void kernel_launch(void* const* d_in, const int* in_sizes, int n_in,
                              void* d_out, int out_size, void* d_ws,
                              size_t ws_size, hipStream_t stream) {
  const float* x = (const float*)d_in[0];
  const float* k_cache = (const float*)d_in[1];
  const float* v_cache = (const float*)d_in[2];
  const float* w_attn = (const float*)d_in[3];
  const float* b_attn = (const float*)d_in[4];
  const float* w_proj = (const float*)d_in[5];
  const float* b_proj = (const float*)d_in[6];
  float* out = (float*)d_out;
  float* ws = (float*)d_ws;

  // workspace layout (floats)
  float* qkv = ws;                          // 8*12288             = 98304
  float* g1p = qkv + 98304;                 // 32*8*12288          = 3145728
  float* apy = g1p + 32 * 8 * THREED;       // 8192*128            = 1048576
  float* apd = apy + 8192 * HDIM;           // 8192
  float* yat = apd + 8192;                  // 8*4096              = 32768
  float* g2p = yat + NB * DMODEL;           // 64*8*4096           = 2097152

  // 1) qkv = x @ w_attn + b_attn   (2 cols/thread, K=4096 split 32x128)
  gemm_skinny_partial<<<dim3(THREED / 512, 32), 256, 0, stream>>>(
      x, w_attn, g1p, DMODEL, THREED, 128);
  gemm_skinny_reduce<<<dim3(NB * THREED / 256), 256, 0, stream>>>(
      g1p, b_attn, qkv, THREED, 32);

  // 2) paged attention partials + reduce
  attn_partial<<<dim3(NPAGES, NHEAD, NB), 256, 0, stream>>>(
      qkv, k_cache, v_cache, apy, apd);
  attn_reduce<<<dim3(NHEAD, NB), 128, 0, stream>>>(qkv, apy, apd, yat);

  // 3) out = yattn @ w_proj + b_proj  (2 cols/thread, K=4096 split 64x64)
  gemm_skinny_partial<<<dim3(DMODEL / 512, 64), 256, 0, stream>>>(
      yat, w_proj, g2p, DMODEL, DMODEL, 64);
  gemm_skinny_reduce<<<dim3(NB * DMODEL / 256), 256, 0, stream>>>(
      g2p, b_proj, out, DMODEL, 64);
}